// Round 22
// baseline (987.351 us; speedup 1.0000x reference)
//
#include <hip/hip_runtime.h>
#include <hip/hip_bf16.h>
#include <math.h>

#define NUM_LAYERS 4
#define D_MODEL 768
#define D_STATE 128
#define D_CONV 4
#define HEADDIM 64
#define D_INNER 1536
#define NHEADS 24
#define CONV_DIM 1792
#define D_PROJ 3352
#define BATCH 4
#define SEQ 2048
#define NROWS (BATCH*SEQ)   /* 8192 */
#define CHUNK 128
#define NCHUNK (SEQ/CHUNK)  /* 16 */
#define LOG2E 1.4426950408889634f

typedef __bf16 bf16x8 __attribute__((ext_vector_type(8)));
typedef float f32x4 __attribute__((ext_vector_type(4)));

#define GLL(gsrc, ldst)                                                        \
  __builtin_amdgcn_global_load_lds(                                            \
      (const __attribute__((address_space(1))) unsigned int*)(gsrc),           \
      (__attribute__((address_space(3))) unsigned int*)(ldst), 16, 0, 0)

__device__ __forceinline__ float warp_reduce_sum(float v) {
  v += __shfl_xor(v, 32);
  v += __shfl_xor(v, 16);
  v += __shfl_xor(v, 8);
  v += __shfl_xor(v, 4);
  v += __shfl_xor(v, 2);
  v += __shfl_xor(v, 1);
  return v;
}

__device__ __forceinline__ float softplusf(float x) {
  return (x > 20.f) ? x : log1pf(expf(x));
}
__device__ __forceinline__ float siluf(float x) {
  return x / (1.f + expf(-x));
}

__device__ __forceinline__ void store_val(float v, float* p) { *p = v; }
__device__ __forceinline__ void store_val(float v, __hip_bfloat16* p) {
  *p = __float2bfloat16(v);
}

// -------------------- rmsnorm over 768 (templated output dtype) ------------
template <typename OUT>
__global__ __launch_bounds__(256) void rmsnorm768_kernel(
    const float* __restrict__ in, const float* __restrict__ w,
    OUT* __restrict__ out, float eps) {
  int row = blockIdx.x;
  const float* x = in + (size_t)row * D_MODEL;
  OUT* o = out + (size_t)row * D_MODEL;
  int t = threadIdx.x;
  float v0 = x[t], v1 = x[t + 256], v2 = x[t + 512];
  float ss = v0 * v0 + v1 * v1 + v2 * v2;
  __shared__ float sred[4];
  ss = warp_reduce_sum(ss);
  if ((t & 63) == 0) sred[t >> 6] = ss;
  __syncthreads();
  float tot = sred[0] + sred[1] + sred[2] + sred[3];
  float inv = rsqrtf(tot / (float)D_MODEL + eps);
  store_val(w[t] * v0 * inv, o + t);
  store_val(w[t + 256] * v1 * inv, o + t + 256);
  store_val(w[t + 512] * v2 * inv, o + t + 512);
}

// ---- FUSED prep: layer-0 rmsnorm (blocks [0,8192)) + f32->bf16 weight ----
// ---- conversion (blocks [8192,10240), grid-stride). Both depend only on ---
// ---- kernel inputs; kernel boundary orders them before layer-0 inproj. ----
__global__ __launch_bounds__(256) void prep0_kernel(
    const float* __restrict__ x, const float* __restrict__ ln_w0,
    __hip_bfloat16* __restrict__ hbuf,
    const float* __restrict__ inw, size_t na, __hip_bfloat16* __restrict__ oa,
    const float* __restrict__ outw, size_t nb, __hip_bfloat16* __restrict__ ob) {
  int bid = blockIdx.x;
  int t = threadIdx.x;
  if (bid < NROWS) {
    const float* xr = x + (size_t)bid * D_MODEL;
    __hip_bfloat16* o = hbuf + (size_t)bid * D_MODEL;
    float v0 = xr[t], v1 = xr[t + 256], v2 = xr[t + 512];
    float ss = v0 * v0 + v1 * v1 + v2 * v2;
    __shared__ float sred[4];
    ss = warp_reduce_sum(ss);
    if ((t & 63) == 0) sred[t >> 6] = ss;
    __syncthreads();
    float tot = sred[0] + sred[1] + sred[2] + sred[3];
    float inv = rsqrtf(tot / (float)D_MODEL + 1e-6f);
    o[t]       = __float2bfloat16(ln_w0[t] * v0 * inv);
    o[t + 256] = __float2bfloat16(ln_w0[t + 256] * v1 * inv);
    o[t + 512] = __float2bfloat16(ln_w0[t + 512] * v2 * inv);
  } else {
    size_t ntot = (na + nb) >> 2;
    int nconv = gridDim.x - NROWS;
    for (size_t q = (size_t)(bid - NROWS) * 256 + t; q < ntot;
         q += (size_t)nconv * 256) {
      size_t i = q << 2;
      const float* src; __hip_bfloat16* dst; size_t off;
      if (i < na) { src = inw; dst = oa; off = i; }
      else        { src = outw; dst = ob; off = i - na; }
      float4 v = *(const float4*)(src + off);
      __hip_bfloat16 h0 = __float2bfloat16(v.x), h1 = __float2bfloat16(v.y);
      __hip_bfloat16 h2 = __float2bfloat16(v.z), h3 = __float2bfloat16(v.w);
      ushort4 u;
      u.x = *(unsigned short*)&h0; u.y = *(unsigned short*)&h1;
      u.z = *(unsigned short*)&h2; u.w = *(unsigned short*)&h3;
      *(ushort4*)(dst + off) = u;
    }
  }
}

#define PH_END()                                                              \
  do {                                                                        \
    __builtin_amdgcn_sched_barrier(0);                                        \
    __builtin_amdgcn_s_barrier();                                             \
    __builtin_amdgcn_sched_barrier(0);                                        \
  } while (0)

// =========== 128x128 MFMA main-loop macro (BK=32, 4 waves) =================
#define GEMM_PROLOGUE_AND_MAINLOOP(Asrc, Wsrc, Kdim)                           \
  int t = threadIdx.x;                                                         \
  int w = t >> 6, l = t & 63;                                                  \
  int NT = (Kdim) >> 5;                                                        \
  int ldsA0 = (w * 64) * 8;                                                    \
  int ldsA1 = (256 + w * 64) * 8;                                              \
  int lr = l & 15, lk = l >> 4;                                                \
  int wr = w >> 1, wc = w & 1;                                                 \
  int aoff = (lk * 128 + wr * 64 + lr) * 8;                                    \
  int boff = (lk * 128 + wc * 64 + lr) * 8;                                    \
  f32x4 acc[4][4];                                                             \
  _Pragma("unroll") for (int i = 0; i < 4; i++)                                \
      _Pragma("unroll") for (int j = 0; j < 4; j++) acc[i][j] = (f32x4)0.f;    \
  STAGE(0, 0);                                                                 \
  for (int kt = 0; kt < NT; ++kt) {                                            \
    int cur = kt & 1;                                                          \
    if (kt + 1 < NT) {                                                         \
      STAGE(cur ^ 1, (kt + 1) * 32);                                           \
      asm volatile("s_waitcnt vmcnt(4)" ::: "memory");                         \
    } else {                                                                   \
      asm volatile("s_waitcnt vmcnt(0)" ::: "memory");                         \
    }                                                                          \
    __builtin_amdgcn_sched_barrier(0);                                         \
    __builtin_amdgcn_s_barrier();                                              \
    __builtin_amdgcn_sched_barrier(0);                                         \
    bf16x8 av[4], bv[4];                                                       \
    _Pragma("unroll") for (int mi = 0; mi < 4; mi++)                           \
        av[mi] = *(const bf16x8*)&At[cur][aoff + mi * 128];                    \
    _Pragma("unroll") for (int ni = 0; ni < 4; ni++)                           \
        bv[ni] = *(const bf16x8*)&Bt[cur][boff + ni * 128];                    \
    __builtin_amdgcn_s_setprio(1);                                             \
    _Pragma("unroll") for (int mi = 0; mi < 4; mi++)                           \
        _Pragma("unroll") for (int ni = 0; ni < 4; ni++)                       \
            acc[mi][ni] = __builtin_amdgcn_mfma_f32_16x16x32_bf16(             \
                av[mi], bv[ni], acc[mi][ni], 0, 0, 0);                         \
    __builtin_amdgcn_s_setprio(0);                                             \
    __builtin_amdgcn_sched_barrier(0);                                         \
    __builtin_amdgcn_s_barrier();                                              \
  }

#define STAGE(buf, kofs)                                                       \
  do {                                                                         \
    GLL(Aptr + (kofs), &At[buf][ldsA0]);                                       \
    GLL(Aptr + (kofs) + 16, &At[buf][ldsA1]);                                  \
    GLL(Wptr + (kofs), &Bt[buf][ldsA0]);                                       \
    GLL(Wptr + (kofs) + 16, &Bt[buf][ldsA1]);                                  \
  } while (0)

// ===== generic GEMM (128x128): C[M][N](f32) = A * W^T (+res) ===============
__global__ __launch_bounds__(256) void gemm_bf16_kernel(
    const __hip_bfloat16* __restrict__ A, const __hip_bfloat16* __restrict__ W,
    const float* __restrict__ res, float* __restrict__ C,
    int M, int N, int K) {
  __shared__ __bf16 At[2][4096];
  __shared__ __bf16 Bt[2][4096];
  int cpx = gridDim.x >> 3;
  int bid = blockIdx.x;
  int bid2 = (bid & 7) * cpx + (bid >> 3);
  int nbn = (N + 127) >> 7;
  int bn = bid2 % nbn;
  int bm = bid2 / nbn;
  int m0 = bm * 128, n0 = bn * 128;
  int srow = threadIdx.x & 127;
  int kbase = (threadIdx.x >> 7) * 8;
  const __hip_bfloat16* Aptr = A + (size_t)(m0 + srow) * K + kbase;
  int nrow = n0 + srow; if (nrow >= N) nrow = N - 1;
  const __hip_bfloat16* Wptr = W + (size_t)nrow * K + kbase;

  GEMM_PROLOGUE_AND_MAINLOOP(A, W, K)

  int rbase = (l >> 4) * 4;
#pragma unroll
  for (int ni = 0; ni < 4; ni++) {
    int n = n0 + wc * 64 + ni * 16 + (l & 15);
    if (n >= N) continue;
#pragma unroll
    for (int mi = 0; mi < 4; mi++) {
#pragma unroll
      for (int r = 0; r < 4; r++) {
        int m = m0 + wr * 64 + mi * 16 + rbase + r;
        float v = acc[mi][ni][r];
        if (res) v += res[(size_t)m * N + n];
        C[(size_t)m * N + n] = v;
      }
    }
  }
}

// ===== in_proj GEMM: 256x256, BK=32, 3-slot distance-2, 8-PHASE interleave =
// (round-14 verified main loop, verbatim) + 2-D XCD chunking: each XCD owns
// an 8bm x 7bn rectangle (XCD grid 4x2, bijective) -> per-XCD L2 footprint
// 8 A-panels (3.15MB) + 7 W-panels (2.6MB) vs 4x14's 1.6+5.2MB.
__global__ __launch_bounds__(512, 1) void gemm_inproj_kernel(
    const __hip_bfloat16* __restrict__ A, const __hip_bfloat16* __restrict__ W,
    __hip_bfloat16* __restrict__ zout, __hip_bfloat16* __restrict__ xout,
    float* __restrict__ dtout) {
  const int K = D_MODEL, N = D_PROJ;      // 768, 3352; NT = 24 K-tiles of 32
  __shared__ __bf16 ring[3][16384];       // 96 KB: per slot A[0,8192) B[8192,16384)
  int bid = blockIdx.x;
  int xcd = bid & 7;
  int q = bid >> 3;                       // 0..55 within XCD
  int bm = (xcd >> 1) * 8 + q / 7;        // XCD grid 4x2: 8bm x 7bn rectangle
  int bn = (xcd & 1) * 7 + q % 7;
  int m0 = bm * 256, n0 = bn * 256;
  int t = threadIdx.x;
  int w = t >> 6, l = t & 63;
  int lr = l & 15, lk = l >> 4;
  int wr = w >> 2, wc = w & 3;            // wave grid 2M x 4N; wave = 128x64

  const __hip_bfloat16* Aptr[2];
  const __hip_bfloat16* Wptr[2];
  int dOff[2];
#pragma unroll
  for (int i = 0; i < 2; i++) {
    int idx = i * 8 + w;
    int oct = idx >> 2, rb = idx & 3;
    dOff[i] = oct * 2048 + rb * 512;
    Aptr[i] = A + (size_t)(m0 + rb * 64 + l) * K + oct * 8;
    int wrow = n0 + rb * 64 + l; if (wrow >= N) wrow = N - 1;
    Wptr[i] = W + (size_t)wrow * K + oct * 8;
  }

#define MFMA4(ACCROW, BV)                                                     \
  do {                                                                        \
    __builtin_amdgcn_s_setprio(1);                                            \
    _Pragma("unroll") for (int mi = 0; mi < 4; mi++)                          \
        acc[(ACCROW) + mi][ci] = __builtin_amdgcn_mfma_f32_16x16x32_bf16(     \
            ((ACCROW) ? av1 : av0)[mi], (BV), acc[(ACCROW) + mi][ci], 0, 0, 0);\
    __builtin_amdgcn_s_setprio(0);                                            \
  } while (0)

  f32x4 acc[8][4];
#pragma unroll
  for (int i = 0; i < 8; i++)
#pragma unroll
    for (int j = 0; j < 4; j++) acc[i][j] = (f32x4)0.f;

  const int NT = 24;
#pragma unroll
  for (int i = 0; i < 2; i++) {
    GLL(Aptr[i], &ring[0][dOff[i]]);
    GLL(Wptr[i], &ring[0][8192 + dOff[i]]);
  }
#pragma unroll
  for (int i = 0; i < 2; i++) {
    GLL(Aptr[i] + 32, &ring[1][dOff[i]]);
    GLL(Wptr[i] + 32, &ring[1][8192 + dOff[i]]);
  }

  for (int kt = 0; kt < NT; ++kt) {
    int s = kt % 3;
    int sn = (kt + 2) % 3;
    bool pf = (kt + 2) < NT;
    if (kt + 1 < NT) {
      asm volatile("s_waitcnt vmcnt(4)" ::: "memory");
    } else {
      asm volatile("s_waitcnt vmcnt(0)" ::: "memory");
    }
    PH_END();

    const __bf16* Ab = &ring[s][0];
    const __bf16* Bb = &ring[s][8192];
    bf16x8 av0[4], av1[4], bv0, bv1, bv2, bv3;
    int ci;
    if (pf) GLL(Aptr[0] + (kt + 2) * 32, &ring[sn][dOff[0]]);
#pragma unroll
    for (int mi = 0; mi < 4; mi++)
      av0[mi] = *(const bf16x8*)&Ab[lk * 2048 + (wr * 128 + mi * 16 + lr) * 8];
    bv0 = *(const bf16x8*)&Bb[lk * 2048 + (wc * 64 + 0 * 16 + lr) * 8];
    ci = 0; MFMA4(0, bv0);
    PH_END();
    if (pf) GLL(Aptr[1] + (kt + 2) * 32, &ring[sn][dOff[1]]);
    bv1 = *(const bf16x8*)&Bb[lk * 2048 + (wc * 64 + 1 * 16 + lr) * 8];
    ci = 1; MFMA4(0, bv1);
    PH_END();
    if (pf) GLL(Wptr[0] + (kt + 2) * 32, &ring[sn][8192 + dOff[0]]);
    bv2 = *(const bf16x8*)&Bb[lk * 2048 + (wc * 64 + 2 * 16 + lr) * 8];
    ci = 2; MFMA4(0, bv2);
    PH_END();
    if (pf) GLL(Wptr[1] + (kt + 2) * 32, &ring[sn][8192 + dOff[1]]);
    bv3 = *(const bf16x8*)&Bb[lk * 2048 + (wc * 64 + 3 * 16 + lr) * 8];
    ci = 3; MFMA4(0, bv3);
    PH_END();
#pragma unroll
    for (int mi = 0; mi < 4; mi++)
      av1[mi] = *(const bf16x8*)&Ab[lk * 2048 + (wr * 128 + (mi + 4) * 16 + lr) * 8];
    ci = 3; MFMA4(4, bv3);
    PH_END();
    ci = 2; MFMA4(4, bv2);
    PH_END();
    ci = 1; MFMA4(4, bv1);
    PH_END();
    ci = 0; MFMA4(4, bv0);
    PH_END();
  }
#undef MFMA4

  int rbase = lk * 4;
  if (bn < 6) {                           // z region
#pragma unroll
    for (int ni = 0; ni < 4; ni++) {
      int n = n0 + wc * 64 + ni * 16 + lr;
#pragma unroll
      for (int mi = 0; mi < 8; mi++)
#pragma unroll
        for (int r = 0; r < 4; r++) {
          int m = m0 + wr * 128 + mi * 16 + rbase + r;
          zout[(size_t)m * D_INNER + n] = __float2bfloat16(acc[mi][ni][r]);
        }
    }
  } else if (bn < 13) {                   // xBC region
    int nb = n0 - D_INNER;
#pragma unroll
    for (int ni = 0; ni < 4; ni++) {
      int n = nb + wc * 64 + ni * 16 + lr;
#pragma unroll
      for (int mi = 0; mi < 8; mi++)
#pragma unroll
        for (int r = 0; r < 4; r++) {
          int m = m0 + wr * 128 + mi * 16 + rbase + r;
          xout[(size_t)m * CONV_DIM + n] = __float2bfloat16(acc[mi][ni][r]);
        }
    }
  } else {                                // dt region: 24 cols
#pragma unroll
    for (int ni = 0; ni < 4; ni++) {
      int loc = wc * 64 + ni * 16 + lr;
      if (loc >= 24) continue;
#pragma unroll
      for (int mi = 0; mi < 8; mi++)
#pragma unroll
        for (int r = 0; r < 4; r++) {
          int m = m0 + wr * 128 + mi * 16 + rbase + r;
          dtout[(size_t)m * 24 + loc] = acc[mi][ni][r];
        }
    }
  }
}

// ======== FUSED conv_tiles + dt: one launch, independent block ranges ======
__global__ __launch_bounds__(256) void conv_dt_kernel(
    const __hip_bfloat16* __restrict__ xbc, const float* __restrict__ cw,
    const float* __restrict__ cb, __hip_bfloat16* __restrict__ xA,
    __hip_bfloat16* __restrict__ Bkt, __hip_bfloat16* __restrict__ Bkn,
    __hip_bfloat16* __restrict__ Ckn,
    const float* __restrict__ dtraw, const float* __restrict__ dt_bias,
    const float* __restrict__ A_log, float* __restrict__ dtbuf,
    float* __restrict__ cum2buf) {
  __shared__ __bf16 srows[11 * CONV_DIM];   // 38.5 KB (dt path aliases this)
  int bid = blockIdx.x;
  int t = threadIdx.x;
  if (bid < BATCH * NCHUNK * 16) {
    int to = bid & 15;
    int c  = (bid >> 4) & 15;
    int b  = bid >> 8;
    int sb = c * CHUNK + to * 8;
    const __hip_bfloat16* base = xbc + (size_t)b * SEQ * CONV_DIM;
    for (int e = t; e < 11 * 224; e += 256) {
      int r = e / 224, c8 = (e - r * 224) * 8;
      int s = sb - 3 + r;
      bf16x8* dst = (bf16x8*)&srows[r * CONV_DIM + c8];
      if (s >= 0) {
        *dst = *(const bf16x8*)&base[(size_t)s * CONV_DIM + c8];
      } else {
        bf16x8 z;
#pragma unroll
        for (int j = 0; j < 8; j++) z[j] = (__bf16)0.f;
        *dst = z;
      }
    }
    __syncthreads();
    int bc = b * 16 + c;
#pragma unroll
    for (int k7 = 0; k7 < 7; k7++) {
      int ch = t + k7 * 256;
      float w0 = cw[ch * 4], w1 = cw[ch * 4 + 1];
      float w2 = cw[ch * 4 + 2], w3 = cw[ch * 4 + 3];
      float bias = cb[ch];
      float out[8];
#pragma unroll
      for (int j = 0; j < 8; j++) {
        float a = bias;
        a = fmaf((float)srows[(j + 0) * CONV_DIM + ch], w0, a);
        a = fmaf((float)srows[(j + 1) * CONV_DIM + ch], w1, a);
        a = fmaf((float)srows[(j + 2) * CONV_DIM + ch], w2, a);
        a = fmaf((float)srows[(j + 3) * CONV_DIM + ch], w3, a);
        out[j] = siluf(a);
      }
      if (ch < D_INNER) {
        int h = ch >> 6, p = ch & 63;
        bf16x8 v;
#pragma unroll
        for (int j = 0; j < 8; j++) v[j] = (__bf16)out[j];
        *(bf16x8*)&xA[((((size_t)bc * 24 + h) * 16 + to) * 64 + p) * 8] = v;
      } else if (ch < D_INNER + D_STATE) {
        int n = ch - D_INNER;
        bf16x8 v;
#pragma unroll
        for (int j = 0; j < 8; j++) v[j] = (__bf16)out[j];
        *(bf16x8*)&Bkt[(((size_t)bc * 16 + to) * 128 + n) * 8] = v;
        __hip_bfloat16* dst = Bkn + (size_t)bc * 16384 + ((n >> 3) * 128) * 8 + (n & 7);
#pragma unroll
        for (int j = 0; j < 8; j++)
          dst[(to * 8 + j) * 8] = __float2bfloat16(out[j]);
      } else {
        int n = ch - D_INNER - D_STATE;
        __hip_bfloat16* dst = Ckn + (size_t)bc * 16384 + ((n >> 3) * 128) * 8 + (n & 7);
#pragma unroll
        for (int j = 0; j < 8; j++)
          dst[(to * 8 + j) * 8] = __float2bfloat16(out[j]);
      }
    }
  } else {
    float* sc = (float*)srows;           // 256 f32 = 1 KB, aliases srows
    int unit = (bid - BATCH * NCHUNK * 16) * 2 + (t >> 7);
    int tt = t & 127;
    int c = unit & 15;
    int h = (unit >> 4) % NHEADS;
    int b = unit / (16 * NHEADS);
    int s = c * CHUNK + tt;
    float Ah = -expf(A_log[h]);
    float raw = dtraw[((size_t)b * SEQ + s) * 24 + h] + dt_bias[h];
    float dt = softplusf(raw);
    sc[t] = dt * Ah;
    __syncthreads();
    for (int off = 1; off < 128; off <<= 1) {
      float v = (tt >= off) ? sc[t - off] : 0.f;
      __syncthreads();
      sc[t] += v;
      __syncthreads();
    }
    size_t o = ((size_t)b * NHEADS + h) * SEQ + s;
    dtbuf[o] = dt;
    cum2buf[o] = sc[t] * LOG2E;
  }
}

// ssd_state: H[p][n] = sum_tau (wdt[tau]*x[tau][p]) * B[tau][n] via MFMA.
__global__ __launch_bounds__(256) void ssd_state_kernel(
    const __hip_bfloat16* __restrict__ xA, const __hip_bfloat16* __restrict__ Bkt,
    const float* __restrict__ dtbuf, const float* __restrict__ cum2buf,
    __hip_bfloat16* __restrict__ states) {
  __shared__ __bf16 sX[8192];
  __shared__ __bf16 sB[16384];
  __shared__ float swdt[128];
  int c = blockIdx.x & 15;
  int h = (blockIdx.x >> 4) % NHEADS;
  int b = blockIdx.x / (16 * NHEADS);
  int t = threadIdx.x;
  int l = t & 63, w = t >> 6;
  const __hip_bfloat16* xsrc = xA + ((size_t)(b * 16 + c) * 24 + h) * 8192;
  const __hip_bfloat16* bsrc = Bkt + (size_t)(b * 16 + c) * 16384;
#pragma unroll
  for (int i = 0; i < 4; i++) GLL(xsrc + (i * 256 + t) * 8, &sX[(i * 256 + t) * 8]);
#pragma unroll
  for (int i = 0; i < 8; i++) GLL(bsrc + (i * 256 + t) * 8, &sB[(i * 256 + t) * 8]);
  {
    size_t dto = ((size_t)b * NHEADS + h) * SEQ + c * CHUNK;
    if (t < 128) {
      float total2 = cum2buf[dto + 127];
      swdt[t] = dtbuf[dto + t] * exp2f(total2 - cum2buf[dto + t]);
    }
  }
  __syncthreads();
#pragma unroll
  for (int i = 0; i < 4; i++) {
    int o = i * 256 + t;
    int to = o >> 6;
    bf16x8 v = *(bf16x8*)&sX[o * 8];
#pragma unroll
    for (int j = 0; j < 8; j++)
      v[j] = (__bf16)((float)v[j] * swdt[to * 8 + j]);
    *(bf16x8*)&sX[o * 8] = v;
  }
  __syncthreads();
  int n0w = w * 32;
  f32x4 acc[4][2];
#pragma unroll
  for (int i = 0; i < 4; i++)
#pragma unroll
    for (int j = 0; j < 2; j++) acc[i][j] = (f32x4)0.f;
#pragma unroll
  for (int kk = 0; kk < 4; kk++) {
    int ko = kk * 4 + (l >> 4);
    bf16x8 av[4], bv[2];
#pragma unroll
    for (int mi = 0; mi < 4; mi++)
      av[mi] = *(const bf16x8*)&sX[(ko * 64 + mi * 16 + (l & 15)) * 8];
#pragma unroll
    for (int ni = 0; ni < 2; ni++)
      bv[ni] = *(const bf16x8*)&sB[(ko * 128 + n0w + ni * 16 + (l & 15)) * 8];
#pragma unroll
    for (int mi = 0; mi < 4; mi++)
#pragma unroll
      for (int ni = 0; ni < 2; ni++)
        acc[mi][ni] = __builtin_amdgcn_mfma_f32_16x16x32_bf16(
            av[mi], bv[ni], acc[mi][ni], 0, 0, 0);
  }
  __hip_bfloat16* dst = states + (((size_t)b * NHEADS + h) * 16 + c) * 8192;
#pragma unroll
  for (int mi = 0; mi < 4; mi++)
#pragma unroll
    for (int ni = 0; ni < 2; ni++) {
      int n = n0w + ni * 16 + (l & 15);
#pragma unroll
      for (int r = 0; r < 4; r++) {
        int p = mi * 16 + (l >> 4) * 4 + r;
        dst[((n >> 3) * 64 + p) * 8 + (n & 7)] = __float2bfloat16(acc[mi][ni][r]);
      }
    }
}

// chunkscan: in-place exclusive prefix over c (16 steps), bf16 tiles.
__global__ __launch_bounds__(256) void ssd_chunkscan_kernel(
    __hip_bfloat16* __restrict__ states, const float* __restrict__ cum2buf) {
  int q = blockIdx.x & 3;
  int bh = blockIdx.x >> 2;
  int t = threadIdx.x;
  int o = q * 256 + t;
  __hip_bfloat16* base = states + (size_t)bh * NCHUNK * 8192 + (size_t)o * 8;
  const float* c2 = cum2buf + (size_t)bh * SEQ;
  float hacc[8];
#pragma unroll
  for (int j = 0; j < 8; j++) hacc[j] = 0.f;
  for (int c = 0; c < NCHUNK; c++) {
    float eA = exp2f(c2[c * 128 + 127]);
    __hip_bfloat16* p = base + (size_t)c * 8192;
    bf16x8 v = *(bf16x8*)p;
    bf16x8 wv;
#pragma unroll
    for (int j = 0; j < 8; j++) {
      float tmp = (float)v[j];
      wv[j] = (__bf16)hacc[j];
      hacc[j] = fmaf(eA, hacc[j], tmp);
    }
    *(bf16x8*)p = wv;
  }
}

// ssd_output: G = C.B^T -> mask/decay in-register -> Y1 = S.x ; Y2 = C.h^T
__global__ __launch_bounds__(256) void ssd_output_kernel(
    const __hip_bfloat16* __restrict__ Ckn, const __hip_bfloat16* __restrict__ Bkn,
    const __hip_bfloat16* __restrict__ xA, const __hip_bfloat16* __restrict__ states,
    const float* __restrict__ dtbuf, const float* __restrict__ cum2buf,
    const float* __restrict__ D_skip, __hip_bfloat16* __restrict__ y) {
  __shared__ __bf16 sC[16384];
  __shared__ __bf16 sBS[16384];
  __shared__ __bf16 sXH[8192];
  int c = blockIdx.x & 15;
  int h = (blockIdx.x >> 4) % NHEADS;
  int b = blockIdx.x / (16 * NHEADS);
  int t = threadIdx.x;
  int l = t & 63, w = t >> 6;
  int bc = b * 16 + c;
  const __hip_bfloat16* csrc = Ckn + (size_t)bc * 16384;
  const __hip_bfloat16* bsrc = Bkn + (size_t)bc * 16384;
  const __hip_bfloat16* xsrc = xA + ((size_t)bc * 24 + h) * 8192;
#pragma unroll
  for (int i = 0; i < 8; i++) GLL(csrc + (i * 256 + t) * 8, &sC[(i * 256 + t) * 8]);
#pragma unroll
  for (int i = 0; i < 8; i++) GLL(bsrc + (i * 256 + t) * 8, &sBS[(i * 256 + t) * 8]);
#pragma unroll
  for (int i = 0; i < 4; i++) GLL(xsrc + (i * 256 + t) * 8, &sXH[(i * 256 + t) * 8]);

  size_t dto = ((size_t)b * NHEADS + h) * SEQ + c * CHUNK;
  float cum2_t[8], cum2_tau[8], dt_tau[8];
#pragma unroll
  for (int fm = 0; fm < 2; fm++)
#pragma unroll
    for (int r = 0; r < 4; r++)
      cum2_t[fm * 4 + r] = cum2buf[dto + w * 32 + fm * 16 + (l >> 4) * 4 + r];
#pragma unroll
  for (int fc = 0; fc < 8; fc++) {
    cum2_tau[fc] = cum2buf[dto + fc * 16 + (l & 15)];
    dt_tau[fc] = dtbuf[dto + fc * 16 + (l & 15)];
  }
  float Dh = D_skip[h];
  __syncthreads();

  f32x4 g[2][8];
#pragma unroll
  for (int i = 0; i < 2; i++)
#pragma unroll
    for (int j = 0; j < 8; j++) g[i][j] = (f32x4)0.f;
#pragma unroll
  for (int kk = 0; kk < 4; kk++) {
    int ko = kk * 4 + (l >> 4);
    bf16x8 a0 = *(const bf16x8*)&sC[(ko * 128 + w * 32 + (l & 15)) * 8];
    bf16x8 a1 = *(const bf16x8*)&sC[(ko * 128 + w * 32 + 16 + (l & 15)) * 8];
#pragma unroll
    for (int fc = 0; fc < 8; fc++) {
      bf16x8 bv = *(const bf16x8*)&sBS[(ko * 128 + fc * 16 + (l & 15)) * 8];
      g[0][fc] = __builtin_amdgcn_mfma_f32_16x16x32_bf16(a0, bv, g[0][fc], 0, 0, 0);
      g[1][fc] = __builtin_amdgcn_mfma_f32_16x16x32_bf16(a1, bv, g[1][fc], 0, 0, 0);
    }
  }
  __syncthreads();  // all waves done reading B before S overwrites it

#pragma unroll
  for (int fm = 0; fm < 2; fm++)
#pragma unroll
    for (int fc = 0; fc < 8; fc++) {
      int tau = fc * 16 + (l & 15);
#pragma unroll
      for (int r = 0; r < 4; r++) {
        int tt = w * 32 + fm * 16 + (l >> 4) * 4 + r;
        float v = 0.f;
        if (tt >= tau) {
          v = exp2f(cum2_t[fm * 4 + r] - cum2_tau[fc]) * dt_tau[fc] * g[fm][fc][r];
          if (tt == tau) v += Dh;
        }
        sBS[((tau >> 3) * 128 + tt) * 8 + (tau & 7)] = (__bf16)v;
      }
    }
  f32x4 y1[2][4];
#pragma unroll
  for (int i = 0; i < 2; i++)
#pragma unroll
    for (int j = 0; j < 4; j++) y1[i][j] = (f32x4)0.f;
#pragma unroll
  for (int kk = 0; kk < 4; kk++) {
    int ko = kk * 4 + (l >> 4);
    bf16x8 a0 = *(const bf16x8*)&sBS[(ko * 128 + w * 32 + (l & 15)) * 8];
    bf16x8 a1 = *(const bf16x8*)&sBS[(ko * 128 + w * 32 + 16 + (l & 15)) * 8];
#pragma unroll
    for (int fc = 0; fc < 4; fc++) {
      bf16x8 bv = *(const bf16x8*)&sXH[(ko * 64 + fc * 16 + (l & 15)) * 8];
      y1[0][fc] = __builtin_amdgcn_mfma_f32_16x16x32_bf16(a0, bv, y1[0][fc], 0, 0, 0);
      y1[1][fc] = __builtin_amdgcn_mfma_f32_16x16x32_bf16(a1, bv, y1[1][fc], 0, 0, 0);
    }
  }
  __syncthreads();  // all waves done with x before h_prev overwrites it
  const __hip_bfloat16* hsrc = states + (((size_t)b * NHEADS + h) * 16 + c) * 8192;
#pragma unroll
  for (int i = 0; i < 4; i++) GLL(hsrc + (i * 256 + t) * 8, &sXH[(i * 256 + t) * 8]);
  __syncthreads();

  f32x4 y2[2][4];
#pragma unroll
  for (int i = 0; i < 2; i++)
#pragma unroll
    for (int j = 0; j < 4; j++) y2[i][j] = (f32x4)0.f;
#pragma unroll
  for (int kk = 0; kk < 4; kk++) {
    int ko = kk * 4 + (l >> 4);
    bf16x8 a0 = *(const bf16x8*)&sC[(ko * 128 + w * 32 + (l & 15)) * 8];
    bf16x8 a1 = *(const bf16x8*)&sC[(ko * 128 + w * 32 + 16 + (l & 15)) * 8];
#pragma unroll
    for (int fc = 0; fc < 4; fc++) {
      bf16x8 bv = *(const bf16x8*)&sXH[(ko * 64 + fc * 16 + (l & 15)) * 8];
      y2[0][fc] = __builtin_amdgcn_mfma_f32_16x16x32_bf16(a0, bv, y2[0][fc], 0, 0, 0);
      y2[1][fc] = __builtin_amdgcn_mfma_f32_16x16x32_bf16(a1, bv, y2[1][fc], 0, 0, 0);
    }
  }

  __hip_bfloat16* yr = y + ((size_t)b * SEQ + c * CHUNK) * D_INNER + h * 64;
#pragma unroll
  for (int fm = 0; fm < 2; fm++)
#pragma unroll
    for (int r = 0; r < 4; r++) {
      int tt = w * 32 + fm * 16 + (l >> 4) * 4 + r;
      float sdec = exp2f(cum2_t[fm * 4 + r]);
#pragma unroll
      for (int fc = 0; fc < 4; fc++) {
        int p = fc * 16 + (l & 15);
        yr[(size_t)tt * D_INNER + p] =
            __float2bfloat16(y1[fm][fc][r] + sdec * y2[fm][fc][r]);
      }
    }
}

// ---- y(bf16) * silu(z bf16) then rmsnorm(1536); 192 thr, bf16x8 ----------
__global__ __launch_bounds__(192) void gate_norm_kernel(
    __hip_bfloat16* __restrict__ y, const __hip_bfloat16* __restrict__ z,
    const float* __restrict__ gw) {
  int row = blockIdx.x;
  const __hip_bfloat16* zr = z + (size_t)row * D_INNER;
  __hip_bfloat16* yr = y + (size_t)row * D_INNER;
  int t = threadIdx.x;
  bf16x8 yv = *(const bf16x8*)&yr[t * 8];
  bf16x8 zv = *(const bf16x8*)&zr[t * 8];
  float4 gw0 = *(const float4*)&gw[t * 8];
  float4 gw1 = *(const float4*)&gw[t * 8 + 4];
  float gwv[8] = {gw0.x, gw0.y, gw0.z, gw0.w, gw1.x, gw1.y, gw1.z, gw1.w};
  float vals[8];
  float ss = 0.f;
#pragma unroll
  for (int j = 0; j < 8; j++) {
    float zf = (float)zv[j];
    float v = (float)yv[j] * siluf(zf);
    vals[j] = v;
    ss += v * v;
  }
  __shared__ float sred[3];
  ss = warp_reduce_sum(ss);
  if ((t & 63) == 0) sred[t >> 6] = ss;
  __syncthreads();
  float tot = sred[0] + sred[1] + sred[2];
  float inv = rsqrtf(tot / (float)D_INNER + 1e-5f);
  bf16x8 o;
#pragma unroll
  for (int j = 0; j < 8; j++)
    o[j] = (__bf16)(gwv[j] * vals[j] * inv);
  *(bf16x8*)&yr[t * 8] = o;
}

// ---------------------------------------------------------------------------
extern "C" void kernel_launch(void* const* d_in, const int* in_sizes, int n_in,
                              void* d_out, int out_size, void* d_ws, size_t ws_size,
                              hipStream_t stream) {
  const float* x          = (const float*)d_in[0];
  const float* in_proj_w  = (const float*)d_in[1];
  const float* conv_w     = (const float*)d_in[2];
  const float* conv_b     = (const float*)d_in[3];
  const float* dt_bias    = (const float*)d_in[4];
  const float* A_log      = (const float*)d_in[5];
  const float* D_skip     = (const float*)d_in[6];
  const float* gnorm_w    = (const float*)d_in[7];
  const float* out_proj_w = (const float*)d_in[8];
  const float* ln_w       = (const float*)d_in[9];
  const float* final_ln_w = (const float*)d_in[10];

  // ws total ~206 MB
  float* ws = (float*)d_ws;
  float* curx   = ws; ws += (size_t)NROWS * D_MODEL;           // 25.2 MB
  float* dtraw  = ws; ws += (size_t)NROWS * 24;                // 0.8
  float* dtbuf  = ws; ws += (size_t)BATCH * NHEADS * SEQ;      // 0.8
  float* cum2   = ws; ws += (size_t)BATCH * NHEADS * SEQ;      // 0.8
  __hip_bfloat16* zbuf   = (__hip_bfloat16*)ws; ws += (size_t)NROWS * D_INNER / 2;   // 25.2
  __hip_bfloat16* xbcbuf = (__hip_bfloat16*)ws; ws += (size_t)NROWS * CONV_DIM / 2;  // 29.4
  __hip_bfloat16* hbuf_b = (__hip_bfloat16*)ws; ws += (size_t)NROWS * D_MODEL / 2;   // 12.6
  __hip_bfloat16* ybuf_b = (__hip_bfloat16*)ws; ws += (size_t)NROWS * D_INNER / 2;   // 25.2
  __hip_bfloat16* wi_b   = (__hip_bfloat16*)ws; ws += (size_t)NUM_LAYERS * D_PROJ * D_MODEL / 2;   // 20.6
  __hip_bfloat16* wo_b   = (__hip_bfloat16*)ws; ws += (size_t)NUM_LAYERS * D_MODEL * D_INNER / 2;  // 9.4
  __hip_bfloat16* xAb    = (__hip_bfloat16*)ws; ws += (size_t)BATCH * NCHUNK * 24 * 8192 / 2; // 25.2
  __hip_bfloat16* Bkt    = (__hip_bfloat16*)ws; ws += (size_t)BATCH * NCHUNK * 16384 / 2;     // 2.1
  __hip_bfloat16* Bkn    = (__hip_bfloat16*)ws; ws += (size_t)BATCH * NCHUNK * 16384 / 2;     // 2.1
  __hip_bfloat16* Ckn    = (__hip_bfloat16*)ws; ws += (size_t)BATCH * NCHUNK * 16384 / 2;     // 2.1
  __hip_bfloat16* states = (__hip_bfloat16*)ws;                                               // 25.2

  // layer-0 rmsnorm + weight conversion fused (both depend only on inputs)
  prep0_kernel<<<NROWS + 2048, 256, 0, stream>>>(
      x, ln_w, hbuf_b,
      in_proj_w, (size_t)NUM_LAYERS * D_PROJ * D_MODEL, wi_b,
      out_proj_w, (size_t)NUM_LAYERS * D_MODEL * D_INNER, wo_b);

  for (int l = 0; l < NUM_LAYERS; l++) {
    const float* xin = (l == 0) ? x : curx;
    if (l > 0) {
      rmsnorm768_kernel<__hip_bfloat16><<<NROWS, 256, 0, stream>>>(
          xin, ln_w + (size_t)l * D_MODEL, hbuf_b, 1e-6f);
    }

    gemm_inproj_kernel<<<448, 512, 0, stream>>>(
        hbuf_b, wi_b + (size_t)l * D_PROJ * D_MODEL, zbuf, xbcbuf, dtraw);

    conv_dt_kernel<<<BATCH * NCHUNK * 16 + BATCH * NHEADS * NCHUNK / 2, 256, 0, stream>>>(
        xbcbuf, conv_w + (size_t)l * CONV_DIM * D_CONV,
        conv_b + (size_t)l * CONV_DIM, xAb, Bkt, Bkn, Ckn,
        dtraw, dt_bias + l * NHEADS, A_log + l * NHEADS, dtbuf, cum2);

    ssd_state_kernel<<<BATCH * NHEADS * NCHUNK, 256, 0, stream>>>(
        xAb, Bkt, dtbuf, cum2, states);

    ssd_chunkscan_kernel<<<BATCH * NHEADS * 4, 256, 0, stream>>>(states, cum2);

    ssd_output_kernel<<<BATCH * NHEADS * NCHUNK, 256, 0, stream>>>(
        Ckn, Bkn, xAb, states, dtbuf, cum2, D_skip + l * NHEADS, ybuf_b);

    gate_norm_kernel<<<NROWS, 192, 0, stream>>>(
        ybuf_b, zbuf, gnorm_w + (size_t)l * D_INNER);

    gemm_bf16_kernel<<<64 * 6, 256, 0, stream>>>(
        ybuf_b, wo_b + (size_t)l * D_MODEL * D_INNER, xin, curx,
        NROWS, D_MODEL, D_INNER);
  }
  rmsnorm768_kernel<float><<<NROWS, 256, 0, stream>>>(
      curx, final_ln_w, (float*)d_out, 1e-6f);
}

// Round 23
// 974.475 us; speedup vs baseline: 1.0132x; 1.0132x over previous
//
#include <hip/hip_runtime.h>
#include <hip/hip_bf16.h>
#include <math.h>

#define NUM_LAYERS 4
#define D_MODEL 768
#define D_STATE 128
#define D_CONV 4
#define HEADDIM 64
#define D_INNER 1536
#define NHEADS 24
#define CONV_DIM 1792
#define D_PROJ 3352
#define BATCH 4
#define SEQ 2048
#define NROWS (BATCH*SEQ)   /* 8192 */
#define CHUNK 128
#define NCHUNK (SEQ/CHUNK)  /* 16 */
#define LOG2E 1.4426950408889634f

typedef __bf16 bf16x8 __attribute__((ext_vector_type(8)));
typedef float f32x4 __attribute__((ext_vector_type(4)));

#define GLL(gsrc, ldst)                                                        \
  __builtin_amdgcn_global_load_lds(                                            \
      (const __attribute__((address_space(1))) unsigned int*)(gsrc),           \
      (__attribute__((address_space(3))) unsigned int*)(ldst), 16, 0, 0)

__device__ __forceinline__ float warp_reduce_sum(float v) {
  v += __shfl_xor(v, 32);
  v += __shfl_xor(v, 16);
  v += __shfl_xor(v, 8);
  v += __shfl_xor(v, 4);
  v += __shfl_xor(v, 2);
  v += __shfl_xor(v, 1);
  return v;
}

__device__ __forceinline__ float softplusf(float x) {
  return (x > 20.f) ? x : log1pf(expf(x));
}
__device__ __forceinline__ float siluf(float x) {
  return x / (1.f + expf(-x));
}

__device__ __forceinline__ void store_val(float v, float* p) { *p = v; }
__device__ __forceinline__ void store_val(float v, __hip_bfloat16* p) {
  *p = __float2bfloat16(v);
}

// ------------- f32 -> bf16 dual-buffer bulk convert (one launch) -----------
__global__ __launch_bounds__(256) void f32_to_bf16_dual_kernel(
    const float* __restrict__ a, size_t na, __hip_bfloat16* __restrict__ oa,
    const float* __restrict__ b, size_t nb, __hip_bfloat16* __restrict__ ob) {
  size_t ntot = (na + nb) >> 2;
  for (size_t q = (size_t)blockIdx.x * 256 + threadIdx.x; q < ntot;
       q += (size_t)gridDim.x * 256) {
    size_t i = q << 2;
    const float* src; __hip_bfloat16* dst; size_t off;
    if (i < na) { src = a; dst = oa; off = i; }
    else        { src = b; dst = ob; off = i - na; }
    float4 v = *(const float4*)(src + off);
    __hip_bfloat16 h0 = __float2bfloat16(v.x), h1 = __float2bfloat16(v.y);
    __hip_bfloat16 h2 = __float2bfloat16(v.z), h3 = __float2bfloat16(v.w);
    ushort4 u;
    u.x = *(unsigned short*)&h0; u.y = *(unsigned short*)&h1;
    u.z = *(unsigned short*)&h2; u.w = *(unsigned short*)&h3;
    *(ushort4*)(dst + off) = u;
  }
}

// -------------------- rmsnorm over 768 (templated output dtype) ------------
template <typename OUT>
__global__ __launch_bounds__(256) void rmsnorm768_kernel(
    const float* __restrict__ in, const float* __restrict__ w,
    OUT* __restrict__ out, float eps) {
  int row = blockIdx.x;
  const float* x = in + (size_t)row * D_MODEL;
  OUT* o = out + (size_t)row * D_MODEL;
  int t = threadIdx.x;
  float v0 = x[t], v1 = x[t + 256], v2 = x[t + 512];
  float ss = v0 * v0 + v1 * v1 + v2 * v2;
  __shared__ float sred[4];
  ss = warp_reduce_sum(ss);
  if ((t & 63) == 0) sred[t >> 6] = ss;
  __syncthreads();
  float tot = sred[0] + sred[1] + sred[2] + sred[3];
  float inv = rsqrtf(tot / (float)D_MODEL + eps);
  store_val(w[t] * v0 * inv, o + t);
  store_val(w[t + 256] * v1 * inv, o + t + 256);
  store_val(w[t + 512] * v2 * inv, o + t + 512);
}

#define PH_END()                                                              \
  do {                                                                        \
    __builtin_amdgcn_sched_barrier(0);                                        \
    __builtin_amdgcn_s_barrier();                                             \
    __builtin_amdgcn_sched_barrier(0);                                        \
  } while (0)

// =========== 128x128 MFMA main-loop macro (BK=32, 4 waves) =================
#define GEMM_PROLOGUE_AND_MAINLOOP(Asrc, Wsrc, Kdim)                           \
  int t = threadIdx.x;                                                         \
  int w = t >> 6, l = t & 63;                                                  \
  int NT = (Kdim) >> 5;                                                        \
  int ldsA0 = (w * 64) * 8;                                                    \
  int ldsA1 = (256 + w * 64) * 8;                                              \
  int lr = l & 15, lk = l >> 4;                                                \
  int wr = w >> 1, wc = w & 1;                                                 \
  int aoff = (lk * 128 + wr * 64 + lr) * 8;                                    \
  int boff = (lk * 128 + wc * 64 + lr) * 8;                                    \
  f32x4 acc[4][4];                                                             \
  _Pragma("unroll") for (int i = 0; i < 4; i++)                                \
      _Pragma("unroll") for (int j = 0; j < 4; j++) acc[i][j] = (f32x4)0.f;    \
  STAGE(0, 0);                                                                 \
  for (int kt = 0; kt < NT; ++kt) {                                            \
    int cur = kt & 1;                                                          \
    if (kt + 1 < NT) {                                                         \
      STAGE(cur ^ 1, (kt + 1) * 32);                                           \
      asm volatile("s_waitcnt vmcnt(4)" ::: "memory");                         \
    } else {                                                                   \
      asm volatile("s_waitcnt vmcnt(0)" ::: "memory");                         \
    }                                                                          \
    __builtin_amdgcn_sched_barrier(0);                                         \
    __builtin_amdgcn_s_barrier();                                              \
    __builtin_amdgcn_sched_barrier(0);                                         \
    bf16x8 av[4], bv[4];                                                       \
    _Pragma("unroll") for (int mi = 0; mi < 4; mi++)                           \
        av[mi] = *(const bf16x8*)&At[cur][aoff + mi * 128];                    \
    _Pragma("unroll") for (int ni = 0; ni < 4; ni++)                           \
        bv[ni] = *(const bf16x8*)&Bt[cur][boff + ni * 128];                    \
    __builtin_amdgcn_s_setprio(1);                                             \
    _Pragma("unroll") for (int mi = 0; mi < 4; mi++)                           \
        _Pragma("unroll") for (int ni = 0; ni < 4; ni++)                       \
            acc[mi][ni] = __builtin_amdgcn_mfma_f32_16x16x32_bf16(             \
                av[mi], bv[ni], acc[mi][ni], 0, 0, 0);                         \
    __builtin_amdgcn_s_setprio(0);                                             \
    __builtin_amdgcn_sched_barrier(0);                                         \
    __builtin_amdgcn_s_barrier();                                              \
  }

#define STAGE(buf, kofs)                                                       \
  do {                                                                         \
    GLL(Aptr + (kofs), &At[buf][ldsA0]);                                       \
    GLL(Aptr + (kofs) + 16, &At[buf][ldsA1]);                                  \
    GLL(Wptr + (kofs), &Bt[buf][ldsA0]);                                       \
    GLL(Wptr + (kofs) + 16, &Bt[buf][ldsA1]);                                  \
  } while (0)

// ===== generic GEMM (128x128): C[M][N](f32) = A * W^T (+res) ===============
__global__ __launch_bounds__(256) void gemm_bf16_kernel(
    const __hip_bfloat16* __restrict__ A, const __hip_bfloat16* __restrict__ W,
    const float* __restrict__ res, float* __restrict__ C,
    int M, int N, int K) {
  __shared__ __bf16 At[2][4096];
  __shared__ __bf16 Bt[2][4096];
  int cpx = gridDim.x >> 3;
  int bid = blockIdx.x;
  int bid2 = (bid & 7) * cpx + (bid >> 3);
  int nbn = (N + 127) >> 7;
  int bn = bid2 % nbn;
  int bm = bid2 / nbn;
  int m0 = bm * 128, n0 = bn * 128;
  int srow = threadIdx.x & 127;
  int kbase = (threadIdx.x >> 7) * 8;
  const __hip_bfloat16* Aptr = A + (size_t)(m0 + srow) * K + kbase;
  int nrow = n0 + srow; if (nrow >= N) nrow = N - 1;
  const __hip_bfloat16* Wptr = W + (size_t)nrow * K + kbase;

  GEMM_PROLOGUE_AND_MAINLOOP(A, W, K)

  int rbase = (l >> 4) * 4;
#pragma unroll
  for (int ni = 0; ni < 4; ni++) {
    int n = n0 + wc * 64 + ni * 16 + (l & 15);
    if (n >= N) continue;
#pragma unroll
    for (int mi = 0; mi < 4; mi++) {
#pragma unroll
      for (int r = 0; r < 4; r++) {
        int m = m0 + wr * 64 + mi * 16 + rbase + r;
        float v = acc[mi][ni][r];
        if (res) v += res[(size_t)m * N + n];
        C[(size_t)m * N + n] = v;
      }
    }
  }
}

// ===== in_proj GEMM: 256x256, BK=32, 3-slot distance-2, 8-PHASE interleave =
// (round-14 verified main loop) + 2-D XCD chunking (round-22 verified):
// each XCD owns an 8bm x 7bn rectangle (XCD grid 4x2, bijective) -> per-XCD
// L2 footprint 3.15+2.6 MB vs 1.6+5.2; measured FETCH 48 -> 34 MB.
__global__ __launch_bounds__(512, 1) void gemm_inproj_kernel(
    const __hip_bfloat16* __restrict__ A, const __hip_bfloat16* __restrict__ W,
    __hip_bfloat16* __restrict__ zout, __hip_bfloat16* __restrict__ xout,
    float* __restrict__ dtout) {
  const int K = D_MODEL, N = D_PROJ;      // 768, 3352; NT = 24 K-tiles of 32
  __shared__ __bf16 ring[3][16384];       // 96 KB: per slot A[0,8192) B[8192,16384)
  int bid = blockIdx.x;
  int xcd = bid & 7;
  int q = bid >> 3;                       // 0..55 within XCD
  int bm = (xcd >> 1) * 8 + q / 7;        // XCD grid 4x2: 8bm x 7bn rectangle
  int bn = (xcd & 1) * 7 + q % 7;
  int m0 = bm * 256, n0 = bn * 256;
  int t = threadIdx.x;
  int w = t >> 6, l = t & 63;
  int lr = l & 15, lk = l >> 4;
  int wr = w >> 2, wc = w & 3;            // wave grid 2M x 4N; wave = 128x64

  const __hip_bfloat16* Aptr[2];
  const __hip_bfloat16* Wptr[2];
  int dOff[2];
#pragma unroll
  for (int i = 0; i < 2; i++) {
    int idx = i * 8 + w;
    int oct = idx >> 2, rb = idx & 3;
    dOff[i] = oct * 2048 + rb * 512;
    Aptr[i] = A + (size_t)(m0 + rb * 64 + l) * K + oct * 8;
    int wrow = n0 + rb * 64 + l; if (wrow >= N) wrow = N - 1;
    Wptr[i] = W + (size_t)wrow * K + oct * 8;
  }

#define MFMA4(ACCROW, BV)                                                     \
  do {                                                                        \
    __builtin_amdgcn_s_setprio(1);                                            \
    _Pragma("unroll") for (int mi = 0; mi < 4; mi++)                          \
        acc[(ACCROW) + mi][ci] = __builtin_amdgcn_mfma_f32_16x16x32_bf16(     \
            ((ACCROW) ? av1 : av0)[mi], (BV), acc[(ACCROW) + mi][ci], 0, 0, 0);\
    __builtin_amdgcn_s_setprio(0);                                            \
  } while (0)

  f32x4 acc[8][4];
#pragma unroll
  for (int i = 0; i < 8; i++)
#pragma unroll
    for (int j = 0; j < 4; j++) acc[i][j] = (f32x4)0.f;

  const int NT = 24;
#pragma unroll
  for (int i = 0; i < 2; i++) {
    GLL(Aptr[i], &ring[0][dOff[i]]);
    GLL(Wptr[i], &ring[0][8192 + dOff[i]]);
  }
#pragma unroll
  for (int i = 0; i < 2; i++) {
    GLL(Aptr[i] + 32, &ring[1][dOff[i]]);
    GLL(Wptr[i] + 32, &ring[1][8192 + dOff[i]]);
  }

  for (int kt = 0; kt < NT; ++kt) {
    int s = kt % 3;
    int sn = (kt + 2) % 3;
    bool pf = (kt + 2) < NT;
    if (kt + 1 < NT) {
      asm volatile("s_waitcnt vmcnt(4)" ::: "memory");
    } else {
      asm volatile("s_waitcnt vmcnt(0)" ::: "memory");
    }
    PH_END();

    const __bf16* Ab = &ring[s][0];
    const __bf16* Bb = &ring[s][8192];
    bf16x8 av0[4], av1[4], bv0, bv1, bv2, bv3;
    int ci;
    if (pf) GLL(Aptr[0] + (kt + 2) * 32, &ring[sn][dOff[0]]);
#pragma unroll
    for (int mi = 0; mi < 4; mi++)
      av0[mi] = *(const bf16x8*)&Ab[lk * 2048 + (wr * 128 + mi * 16 + lr) * 8];
    bv0 = *(const bf16x8*)&Bb[lk * 2048 + (wc * 64 + 0 * 16 + lr) * 8];
    ci = 0; MFMA4(0, bv0);
    PH_END();
    if (pf) GLL(Aptr[1] + (kt + 2) * 32, &ring[sn][dOff[1]]);
    bv1 = *(const bf16x8*)&Bb[lk * 2048 + (wc * 64 + 1 * 16 + lr) * 8];
    ci = 1; MFMA4(0, bv1);
    PH_END();
    if (pf) GLL(Wptr[0] + (kt + 2) * 32, &ring[sn][8192 + dOff[0]]);
    bv2 = *(const bf16x8*)&Bb[lk * 2048 + (wc * 64 + 2 * 16 + lr) * 8];
    ci = 2; MFMA4(0, bv2);
    PH_END();
    if (pf) GLL(Wptr[1] + (kt + 2) * 32, &ring[sn][8192 + dOff[1]]);
    bv3 = *(const bf16x8*)&Bb[lk * 2048 + (wc * 64 + 3 * 16 + lr) * 8];
    ci = 3; MFMA4(0, bv3);
    PH_END();
#pragma unroll
    for (int mi = 0; mi < 4; mi++)
      av1[mi] = *(const bf16x8*)&Ab[lk * 2048 + (wr * 128 + (mi + 4) * 16 + lr) * 8];
    ci = 3; MFMA4(4, bv3);
    PH_END();
    ci = 2; MFMA4(4, bv2);
    PH_END();
    ci = 1; MFMA4(4, bv1);
    PH_END();
    ci = 0; MFMA4(4, bv0);
    PH_END();
  }
#undef MFMA4

  int rbase = lk * 4;
  if (bn < 6) {                           // z region
#pragma unroll
    for (int ni = 0; ni < 4; ni++) {
      int n = n0 + wc * 64 + ni * 16 + lr;
#pragma unroll
      for (int mi = 0; mi < 8; mi++)
#pragma unroll
        for (int r = 0; r < 4; r++) {
          int m = m0 + wr * 128 + mi * 16 + rbase + r;
          zout[(size_t)m * D_INNER + n] = __float2bfloat16(acc[mi][ni][r]);
        }
    }
  } else if (bn < 13) {                   // xBC region
    int nb = n0 - D_INNER;
#pragma unroll
    for (int ni = 0; ni < 4; ni++) {
      int n = nb + wc * 64 + ni * 16 + lr;
#pragma unroll
      for (int mi = 0; mi < 8; mi++)
#pragma unroll
        for (int r = 0; r < 4; r++) {
          int m = m0 + wr * 128 + mi * 16 + rbase + r;
          xout[(size_t)m * CONV_DIM + n] = __float2bfloat16(acc[mi][ni][r]);
        }
    }
  } else {                                // dt region: 24 cols
#pragma unroll
    for (int ni = 0; ni < 4; ni++) {
      int loc = wc * 64 + ni * 16 + lr;
      if (loc >= 24) continue;
#pragma unroll
      for (int mi = 0; mi < 8; mi++)
#pragma unroll
        for (int r = 0; r < 4; r++) {
          int m = m0 + wr * 128 + mi * 16 + rbase + r;
          dtout[(size_t)m * 24 + loc] = acc[mi][ni][r];
        }
    }
  }
}

// ======== FUSED conv_tiles + dt: one launch, independent block ranges ======
__global__ __launch_bounds__(256) void conv_dt_kernel(
    const __hip_bfloat16* __restrict__ xbc, const float* __restrict__ cw,
    const float* __restrict__ cb, __hip_bfloat16* __restrict__ xA,
    __hip_bfloat16* __restrict__ Bkt, __hip_bfloat16* __restrict__ Bkn,
    __hip_bfloat16* __restrict__ Ckn,
    const float* __restrict__ dtraw, const float* __restrict__ dt_bias,
    const float* __restrict__ A_log, float* __restrict__ dtbuf,
    float* __restrict__ cum2buf) {
  __shared__ __bf16 srows[11 * CONV_DIM];   // 38.5 KB (dt path aliases this)
  int bid = blockIdx.x;
  int t = threadIdx.x;
  if (bid < BATCH * NCHUNK * 16) {
    int to = bid & 15;
    int c  = (bid >> 4) & 15;
    int b  = bid >> 8;
    int sb = c * CHUNK + to * 8;
    const __hip_bfloat16* base = xbc + (size_t)b * SEQ * CONV_DIM;
    for (int e = t; e < 11 * 224; e += 256) {
      int r = e / 224, c8 = (e - r * 224) * 8;
      int s = sb - 3 + r;
      bf16x8* dst = (bf16x8*)&srows[r * CONV_DIM + c8];
      if (s >= 0) {
        *dst = *(const bf16x8*)&base[(size_t)s * CONV_DIM + c8];
      } else {
        bf16x8 z;
#pragma unroll
        for (int j = 0; j < 8; j++) z[j] = (__bf16)0.f;
        *dst = z;
      }
    }
    __syncthreads();
    int bc = b * 16 + c;
#pragma unroll
    for (int k7 = 0; k7 < 7; k7++) {
      int ch = t + k7 * 256;
      float w0 = cw[ch * 4], w1 = cw[ch * 4 + 1];
      float w2 = cw[ch * 4 + 2], w3 = cw[ch * 4 + 3];
      float bias = cb[ch];
      float out[8];
#pragma unroll
      for (int j = 0; j < 8; j++) {
        float a = bias;
        a = fmaf((float)srows[(j + 0) * CONV_DIM + ch], w0, a);
        a = fmaf((float)srows[(j + 1) * CONV_DIM + ch], w1, a);
        a = fmaf((float)srows[(j + 2) * CONV_DIM + ch], w2, a);
        a = fmaf((float)srows[(j + 3) * CONV_DIM + ch], w3, a);
        out[j] = siluf(a);
      }
      if (ch < D_INNER) {
        int h = ch >> 6, p = ch & 63;
        bf16x8 v;
#pragma unroll
        for (int j = 0; j < 8; j++) v[j] = (__bf16)out[j];
        *(bf16x8*)&xA[((((size_t)bc * 24 + h) * 16 + to) * 64 + p) * 8] = v;
      } else if (ch < D_INNER + D_STATE) {
        int n = ch - D_INNER;
        bf16x8 v;
#pragma unroll
        for (int j = 0; j < 8; j++) v[j] = (__bf16)out[j];
        *(bf16x8*)&Bkt[(((size_t)bc * 16 + to) * 128 + n) * 8] = v;
        __hip_bfloat16* dst = Bkn + (size_t)bc * 16384 + ((n >> 3) * 128) * 8 + (n & 7);
#pragma unroll
        for (int j = 0; j < 8; j++)
          dst[(to * 8 + j) * 8] = __float2bfloat16(out[j]);
      } else {
        int n = ch - D_INNER - D_STATE;
        __hip_bfloat16* dst = Ckn + (size_t)bc * 16384 + ((n >> 3) * 128) * 8 + (n & 7);
#pragma unroll
        for (int j = 0; j < 8; j++)
          dst[(to * 8 + j) * 8] = __float2bfloat16(out[j]);
      }
    }
  } else {
    float* sc = (float*)srows;           // 256 f32 = 1 KB, aliases srows
    int unit = (bid - BATCH * NCHUNK * 16) * 2 + (t >> 7);
    int tt = t & 127;
    int c = unit & 15;
    int h = (unit >> 4) % NHEADS;
    int b = unit / (16 * NHEADS);
    int s = c * CHUNK + tt;
    float Ah = -expf(A_log[h]);
    float raw = dtraw[((size_t)b * SEQ + s) * 24 + h] + dt_bias[h];
    float dt = softplusf(raw);
    sc[t] = dt * Ah;
    __syncthreads();
    for (int off = 1; off < 128; off <<= 1) {
      float v = (tt >= off) ? sc[t - off] : 0.f;
      __syncthreads();
      sc[t] += v;
      __syncthreads();
    }
    size_t o = ((size_t)b * NHEADS + h) * SEQ + s;
    dtbuf[o] = dt;
    cum2buf[o] = sc[t] * LOG2E;
  }
}

// ssd_state: H[p][n] = sum_tau (wdt[tau]*x[tau][p]) * B[tau][n] via MFMA.
__global__ __launch_bounds__(256) void ssd_state_kernel(
    const __hip_bfloat16* __restrict__ xA, const __hip_bfloat16* __restrict__ Bkt,
    const float* __restrict__ dtbuf, const float* __restrict__ cum2buf,
    __hip_bfloat16* __restrict__ states) {
  __shared__ __bf16 sX[8192];
  __shared__ __bf16 sB[16384];
  __shared__ float swdt[128];
  int c = blockIdx.x & 15;
  int h = (blockIdx.x >> 4) % NHEADS;
  int b = blockIdx.x / (16 * NHEADS);
  int t = threadIdx.x;
  int l = t & 63, w = t >> 6;
  const __hip_bfloat16* xsrc = xA + ((size_t)(b * 16 + c) * 24 + h) * 8192;
  const __hip_bfloat16* bsrc = Bkt + (size_t)(b * 16 + c) * 16384;
#pragma unroll
  for (int i = 0; i < 4; i++) GLL(xsrc + (i * 256 + t) * 8, &sX[(i * 256 + t) * 8]);
#pragma unroll
  for (int i = 0; i < 8; i++) GLL(bsrc + (i * 256 + t) * 8, &sB[(i * 256 + t) * 8]);
  {
    size_t dto = ((size_t)b * NHEADS + h) * SEQ + c * CHUNK;
    if (t < 128) {
      float total2 = cum2buf[dto + 127];
      swdt[t] = dtbuf[dto + t] * exp2f(total2 - cum2buf[dto + t]);
    }
  }
  __syncthreads();
#pragma unroll
  for (int i = 0; i < 4; i++) {
    int o = i * 256 + t;
    int to = o >> 6;
    bf16x8 v = *(bf16x8*)&sX[o * 8];
#pragma unroll
    for (int j = 0; j < 8; j++)
      v[j] = (__bf16)((float)v[j] * swdt[to * 8 + j]);
    *(bf16x8*)&sX[o * 8] = v;
  }
  __syncthreads();
  int n0w = w * 32;
  f32x4 acc[4][2];
#pragma unroll
  for (int i = 0; i < 4; i++)
#pragma unroll
    for (int j = 0; j < 2; j++) acc[i][j] = (f32x4)0.f;
#pragma unroll
  for (int kk = 0; kk < 4; kk++) {
    int ko = kk * 4 + (l >> 4);
    bf16x8 av[4], bv[2];
#pragma unroll
    for (int mi = 0; mi < 4; mi++)
      av[mi] = *(const bf16x8*)&sX[(ko * 64 + mi * 16 + (l & 15)) * 8];
#pragma unroll
    for (int ni = 0; ni < 2; ni++)
      bv[ni] = *(const bf16x8*)&sB[(ko * 128 + n0w + ni * 16 + (l & 15)) * 8];
#pragma unroll
    for (int mi = 0; mi < 4; mi++)
#pragma unroll
      for (int ni = 0; ni < 2; ni++)
        acc[mi][ni] = __builtin_amdgcn_mfma_f32_16x16x32_bf16(
            av[mi], bv[ni], acc[mi][ni], 0, 0, 0);
  }
  __hip_bfloat16* dst = states + (((size_t)b * NHEADS + h) * 16 + c) * 8192;
#pragma unroll
  for (int mi = 0; mi < 4; mi++)
#pragma unroll
    for (int ni = 0; ni < 2; ni++) {
      int n = n0w + ni * 16 + (l & 15);
#pragma unroll
      for (int r = 0; r < 4; r++) {
        int p = mi * 16 + (l >> 4) * 4 + r;
        dst[((n >> 3) * 64 + p) * 8 + (n & 7)] = __float2bfloat16(acc[mi][ni][r]);
      }
    }
}

// chunkscan: in-place exclusive prefix over c (16 steps), bf16 tiles.
__global__ __launch_bounds__(256) void ssd_chunkscan_kernel(
    __hip_bfloat16* __restrict__ states, const float* __restrict__ cum2buf) {
  int q = blockIdx.x & 3;
  int bh = blockIdx.x >> 2;
  int t = threadIdx.x;
  int o = q * 256 + t;
  __hip_bfloat16* base = states + (size_t)bh * NCHUNK * 8192 + (size_t)o * 8;
  const float* c2 = cum2buf + (size_t)bh * SEQ;
  float hacc[8];
#pragma unroll
  for (int j = 0; j < 8; j++) hacc[j] = 0.f;
  for (int c = 0; c < NCHUNK; c++) {
    float eA = exp2f(c2[c * 128 + 127]);
    __hip_bfloat16* p = base + (size_t)c * 8192;
    bf16x8 v = *(bf16x8*)p;
    bf16x8 wv;
#pragma unroll
    for (int j = 0; j < 8; j++) {
      float tmp = (float)v[j];
      wv[j] = (__bf16)hacc[j];
      hacc[j] = fmaf(eA, hacc[j], tmp);
    }
    *(bf16x8*)p = wv;
  }
}

// ssd_output: G = C.B^T -> mask/decay in-register -> Y1 = S.x ; Y2 = C.h^T
__global__ __launch_bounds__(256) void ssd_output_kernel(
    const __hip_bfloat16* __restrict__ Ckn, const __hip_bfloat16* __restrict__ Bkn,
    const __hip_bfloat16* __restrict__ xA, const __hip_bfloat16* __restrict__ states,
    const float* __restrict__ dtbuf, const float* __restrict__ cum2buf,
    const float* __restrict__ D_skip, __hip_bfloat16* __restrict__ y) {
  __shared__ __bf16 sC[16384];
  __shared__ __bf16 sBS[16384];
  __shared__ __bf16 sXH[8192];
  int c = blockIdx.x & 15;
  int h = (blockIdx.x >> 4) % NHEADS;
  int b = blockIdx.x / (16 * NHEADS);
  int t = threadIdx.x;
  int l = t & 63, w = t >> 6;
  int bc = b * 16 + c;
  const __hip_bfloat16* csrc = Ckn + (size_t)bc * 16384;
  const __hip_bfloat16* bsrc = Bkn + (size_t)bc * 16384;
  const __hip_bfloat16* xsrc = xA + ((size_t)bc * 24 + h) * 8192;
#pragma unroll
  for (int i = 0; i < 8; i++) GLL(csrc + (i * 256 + t) * 8, &sC[(i * 256 + t) * 8]);
#pragma unroll
  for (int i = 0; i < 8; i++) GLL(bsrc + (i * 256 + t) * 8, &sBS[(i * 256 + t) * 8]);
#pragma unroll
  for (int i = 0; i < 4; i++) GLL(xsrc + (i * 256 + t) * 8, &sXH[(i * 256 + t) * 8]);

  size_t dto = ((size_t)b * NHEADS + h) * SEQ + c * CHUNK;
  float cum2_t[8], cum2_tau[8], dt_tau[8];
#pragma unroll
  for (int fm = 0; fm < 2; fm++)
#pragma unroll
    for (int r = 0; r < 4; r++)
      cum2_t[fm * 4 + r] = cum2buf[dto + w * 32 + fm * 16 + (l >> 4) * 4 + r];
#pragma unroll
  for (int fc = 0; fc < 8; fc++) {
    cum2_tau[fc] = cum2buf[dto + fc * 16 + (l & 15)];
    dt_tau[fc] = dtbuf[dto + fc * 16 + (l & 15)];
  }
  float Dh = D_skip[h];
  __syncthreads();

  f32x4 g[2][8];
#pragma unroll
  for (int i = 0; i < 2; i++)
#pragma unroll
    for (int j = 0; j < 8; j++) g[i][j] = (f32x4)0.f;
#pragma unroll
  for (int kk = 0; kk < 4; kk++) {
    int ko = kk * 4 + (l >> 4);
    bf16x8 a0 = *(const bf16x8*)&sC[(ko * 128 + w * 32 + (l & 15)) * 8];
    bf16x8 a1 = *(const bf16x8*)&sC[(ko * 128 + w * 32 + 16 + (l & 15)) * 8];
#pragma unroll
    for (int fc = 0; fc < 8; fc++) {
      bf16x8 bv = *(const bf16x8*)&sBS[(ko * 128 + fc * 16 + (l & 15)) * 8];
      g[0][fc] = __builtin_amdgcn_mfma_f32_16x16x32_bf16(a0, bv, g[0][fc], 0, 0, 0);
      g[1][fc] = __builtin_amdgcn_mfma_f32_16x16x32_bf16(a1, bv, g[1][fc], 0, 0, 0);
    }
  }
  __syncthreads();  // all waves done reading B before S overwrites it

#pragma unroll
  for (int fm = 0; fm < 2; fm++)
#pragma unroll
    for (int fc = 0; fc < 8; fc++) {
      int tau = fc * 16 + (l & 15);
#pragma unroll
      for (int r = 0; r < 4; r++) {
        int tt = w * 32 + fm * 16 + (l >> 4) * 4 + r;
        float v = 0.f;
        if (tt >= tau) {
          v = exp2f(cum2_t[fm * 4 + r] - cum2_tau[fc]) * dt_tau[fc] * g[fm][fc][r];
          if (tt == tau) v += Dh;
        }
        sBS[((tau >> 3) * 128 + tt) * 8 + (tau & 7)] = (__bf16)v;
      }
    }
  f32x4 y1[2][4];
#pragma unroll
  for (int i = 0; i < 2; i++)
#pragma unroll
    for (int j = 0; j < 4; j++) y1[i][j] = (f32x4)0.f;
#pragma unroll
  for (int kk = 0; kk < 4; kk++) {
    int ko = kk * 4 + (l >> 4);
    bf16x8 a0 = *(const bf16x8*)&sBS[(ko * 128 + w * 32 + (l & 15)) * 8];
    bf16x8 a1 = *(const bf16x8*)&sBS[(ko * 128 + w * 32 + 16 + (l & 15)) * 8];
#pragma unroll
    for (int fc = 0; fc < 4; fc++) {
      bf16x8 bv = *(const bf16x8*)&sXH[(ko * 64 + fc * 16 + (l & 15)) * 8];
      y1[0][fc] = __builtin_amdgcn_mfma_f32_16x16x32_bf16(a0, bv, y1[0][fc], 0, 0, 0);
      y1[1][fc] = __builtin_amdgcn_mfma_f32_16x16x32_bf16(a1, bv, y1[1][fc], 0, 0, 0);
    }
  }
  __syncthreads();  // all waves done with x before h_prev overwrites it
  const __hip_bfloat16* hsrc = states + (((size_t)b * NHEADS + h) * 16 + c) * 8192;
#pragma unroll
  for (int i = 0; i < 4; i++) GLL(hsrc + (i * 256 + t) * 8, &sXH[(i * 256 + t) * 8]);
  __syncthreads();

  f32x4 y2[2][4];
#pragma unroll
  for (int i = 0; i < 2; i++)
#pragma unroll
    for (int j = 0; j < 4; j++) y2[i][j] = (f32x4)0.f;
#pragma unroll
  for (int kk = 0; kk < 4; kk++) {
    int ko = kk * 4 + (l >> 4);
    bf16x8 a0 = *(const bf16x8*)&sC[(ko * 128 + w * 32 + (l & 15)) * 8];
    bf16x8 a1 = *(const bf16x8*)&sC[(ko * 128 + w * 32 + 16 + (l & 15)) * 8];
#pragma unroll
    for (int fc = 0; fc < 4; fc++) {
      bf16x8 bv = *(const bf16x8*)&sXH[(ko * 64 + fc * 16 + (l & 15)) * 8];
      y2[0][fc] = __builtin_amdgcn_mfma_f32_16x16x32_bf16(a0, bv, y2[0][fc], 0, 0, 0);
      y2[1][fc] = __builtin_amdgcn_mfma_f32_16x16x32_bf16(a1, bv, y2[1][fc], 0, 0, 0);
    }
  }

  __hip_bfloat16* yr = y + ((size_t)b * SEQ + c * CHUNK) * D_INNER + h * 64;
#pragma unroll
  for (int fm = 0; fm < 2; fm++)
#pragma unroll
    for (int r = 0; r < 4; r++) {
      int tt = w * 32 + fm * 16 + (l >> 4) * 4 + r;
      float sdec = exp2f(cum2_t[fm * 4 + r]);
#pragma unroll
      for (int fc = 0; fc < 4; fc++) {
        int p = fc * 16 + (l & 15);
        yr[(size_t)tt * D_INNER + p] =
            __float2bfloat16(y1[fm][fc][r] + sdec * y2[fm][fc][r]);
      }
    }
}

// ---- y(bf16) * silu(z bf16) then rmsnorm(1536); 192 thr, bf16x8 ----------
__global__ __launch_bounds__(192) void gate_norm_kernel(
    __hip_bfloat16* __restrict__ y, const __hip_bfloat16* __restrict__ z,
    const float* __restrict__ gw) {
  int row = blockIdx.x;
  const __hip_bfloat16* zr = z + (size_t)row * D_INNER;
  __hip_bfloat16* yr = y + (size_t)row * D_INNER;
  int t = threadIdx.x;
  bf16x8 yv = *(const bf16x8*)&yr[t * 8];
  bf16x8 zv = *(const bf16x8*)&zr[t * 8];
  float4 gw0 = *(const float4*)&gw[t * 8];
  float4 gw1 = *(const float4*)&gw[t * 8 + 4];
  float gwv[8] = {gw0.x, gw0.y, gw0.z, gw0.w, gw1.x, gw1.y, gw1.z, gw1.w};
  float vals[8];
  float ss = 0.f;
#pragma unroll
  for (int j = 0; j < 8; j++) {
    float zf = (float)zv[j];
    float v = (float)yv[j] * siluf(zf);
    vals[j] = v;
    ss += v * v;
  }
  __shared__ float sred[3];
  ss = warp_reduce_sum(ss);
  if ((t & 63) == 0) sred[t >> 6] = ss;
  __syncthreads();
  float tot = sred[0] + sred[1] + sred[2];
  float inv = rsqrtf(tot / (float)D_INNER + 1e-5f);
  bf16x8 o;
#pragma unroll
  for (int j = 0; j < 8; j++)
    o[j] = (__bf16)(gwv[j] * vals[j] * inv);
  *(bf16x8*)&yr[t * 8] = o;
}

// ---------------------------------------------------------------------------
extern "C" void kernel_launch(void* const* d_in, const int* in_sizes, int n_in,
                              void* d_out, int out_size, void* d_ws, size_t ws_size,
                              hipStream_t stream) {
  const float* x          = (const float*)d_in[0];
  const float* in_proj_w  = (const float*)d_in[1];
  const float* conv_w     = (const float*)d_in[2];
  const float* conv_b     = (const float*)d_in[3];
  const float* dt_bias    = (const float*)d_in[4];
  const float* A_log      = (const float*)d_in[5];
  const float* D_skip     = (const float*)d_in[6];
  const float* gnorm_w    = (const float*)d_in[7];
  const float* out_proj_w = (const float*)d_in[8];
  const float* ln_w       = (const float*)d_in[9];
  const float* final_ln_w = (const float*)d_in[10];

  // ws total ~206 MB
  float* ws = (float*)d_ws;
  float* curx   = ws; ws += (size_t)NROWS * D_MODEL;           // 25.2 MB
  float* dtraw  = ws; ws += (size_t)NROWS * 24;                // 0.8
  float* dtbuf  = ws; ws += (size_t)BATCH * NHEADS * SEQ;      // 0.8
  float* cum2   = ws; ws += (size_t)BATCH * NHEADS * SEQ;      // 0.8
  __hip_bfloat16* zbuf   = (__hip_bfloat16*)ws; ws += (size_t)NROWS * D_INNER / 2;   // 25.2
  __hip_bfloat16* xbcbuf = (__hip_bfloat16*)ws; ws += (size_t)NROWS * CONV_DIM / 2;  // 29.4
  __hip_bfloat16* hbuf_b = (__hip_bfloat16*)ws; ws += (size_t)NROWS * D_MODEL / 2;   // 12.6
  __hip_bfloat16* ybuf_b = (__hip_bfloat16*)ws; ws += (size_t)NROWS * D_INNER / 2;   // 25.2
  __hip_bfloat16* wi_b   = (__hip_bfloat16*)ws; ws += (size_t)NUM_LAYERS * D_PROJ * D_MODEL / 2;   // 20.6
  __hip_bfloat16* wo_b   = (__hip_bfloat16*)ws; ws += (size_t)NUM_LAYERS * D_MODEL * D_INNER / 2;  // 9.4
  __hip_bfloat16* xAb    = (__hip_bfloat16*)ws; ws += (size_t)BATCH * NCHUNK * 24 * 8192 / 2; // 25.2
  __hip_bfloat16* Bkt    = (__hip_bfloat16*)ws; ws += (size_t)BATCH * NCHUNK * 16384 / 2;     // 2.1
  __hip_bfloat16* Bkn    = (__hip_bfloat16*)ws; ws += (size_t)BATCH * NCHUNK * 16384 / 2;     // 2.1
  __hip_bfloat16* Ckn    = (__hip_bfloat16*)ws; ws += (size_t)BATCH * NCHUNK * 16384 / 2;     // 2.1
  __hip_bfloat16* states = (__hip_bfloat16*)ws;                                               // 25.2

  // convert first so it overlaps with layer-0 rmsnorm (round-21 ordering)
  f32_to_bf16_dual_kernel<<<2048, 256, 0, stream>>>(
      in_proj_w, (size_t)NUM_LAYERS * D_PROJ * D_MODEL, wi_b,
      out_proj_w, (size_t)NUM_LAYERS * D_MODEL * D_INNER, wo_b);

  for (int l = 0; l < NUM_LAYERS; l++) {
    const float* xin = (l == 0) ? x : curx;
    rmsnorm768_kernel<__hip_bfloat16><<<NROWS, 256, 0, stream>>>(
        xin, ln_w + (size_t)l * D_MODEL, hbuf_b, 1e-6f);

    gemm_inproj_kernel<<<448, 512, 0, stream>>>(
        hbuf_b, wi_b + (size_t)l * D_PROJ * D_MODEL, zbuf, xbcbuf, dtraw);

    conv_dt_kernel<<<BATCH * NCHUNK * 16 + BATCH * NHEADS * NCHUNK / 2, 256, 0, stream>>>(
        xbcbuf, conv_w + (size_t)l * CONV_DIM * D_CONV,
        conv_b + (size_t)l * CONV_DIM, xAb, Bkt, Bkn, Ckn,
        dtraw, dt_bias + l * NHEADS, A_log + l * NHEADS, dtbuf, cum2);

    ssd_state_kernel<<<BATCH * NHEADS * NCHUNK, 256, 0, stream>>>(
        xAb, Bkt, dtbuf, cum2, states);

    ssd_chunkscan_kernel<<<BATCH * NHEADS * 4, 256, 0, stream>>>(states, cum2);

    ssd_output_kernel<<<BATCH * NHEADS * NCHUNK, 256, 0, stream>>>(
        Ckn, Bkn, xAb, states, dtbuf, cum2, D_skip + l * NHEADS, ybuf_b);

    gate_norm_kernel<<<NROWS, 192, 0, stream>>>(
        ybuf_b, zbuf, gnorm_w + (size_t)l * D_INNER);

    gemm_bf16_kernel<<<64 * 6, 256, 0, stream>>>(
        ybuf_b, wo_b + (size_t)l * D_MODEL * D_INNER, xin, curx,
        NROWS, D_MODEL, D_INNER);
  }
  rmsnorm768_kernel<float><<<NROWS, 256, 0, stream>>>(
      curx, final_ln_w, (float*)d_out, 1e-6f);
}